// Round 6
// baseline (239.779 us; speedup 1.0000x reference)
//
#include <hip/hip_runtime.h>

#define N_ELEM 16777216
#define K 32                        // elements per thread-chunk
#define BLOCK 256
#define TILE (BLOCK * K)            // 8192 elements per block
#define NBLK (N_ELEM / TILE)        // 2048 blocks
#define INV_N (1.0 / (double)N_ELEM)

__global__ __launch_bounds__(BLOCK) void k1_all(
        const float4* __restrict__ in4, const int4* __restrict__ lab4,
        const int* __restrict__ labs, float* __restrict__ out) {
    __shared__ unsigned metaS[BLOCK];   // h(6b) | firstLab<<6 | lastLab<<7
    __shared__ double wsum[BLOCK / 64];
    const int tid = threadIdx.x;
    const long long ch = (long long)blockIdx.x * BLOCK + tid;   // global chunk id

    // ---- phase A: issue ALL of this thread's loads before any use (MLP) ----
    float4 x[16];                       // 32 elements x 2 logits
    int4   lv[8];                       // 32 labels
    const float4* ip = in4 + ch * 16;
    const int4*   lp = lab4 + ch * 8;
    #pragma unroll
    for (int j = 0; j < 16; ++j) x[j] = ip[j];
    #pragma unroll
    for (int j = 0; j < 8; ++j) lv[j] = lp[j];

    // ---- phase B: backward run-scan entirely in registers ----
    float acc = 0.f, tce = 0.f, cf = 0.f;
    int prevLab = 0, lastLab = 0, firstLab = 0;
    #pragma unroll
    for (int i = K - 1; i >= 0; --i) {
        float a = (i & 1) ? x[i >> 1].z : x[i >> 1].x;   // class-0 logit
        float b = (i & 1) ? x[i >> 1].w : x[i >> 1].y;   // class-1 logit
        int m = i & 3, l;
        { int4 q = lv[i >> 2];
          l = (m == 0) ? q.x : (m == 1) ? q.y : (m == 2) ? q.z : q.w; }
        float d = l ? (a - b) : (b - a);                 // x_other - x_label
        float ce = __logf(1.0f + __expf(d));             // CE = softplus(d)
        if (i == K - 1) { cf = 1.f; lastLab = l; }
        else            cf = (l == prevLab) ? cf + 1.f : 1.f;
        acc = fmaf(ce, cf, acc);                         // chunk-truncated weight
        if (cf == (float)(K - i)) tce += ce;             // element in trailing run
        prevLab = l;
        firstLab = l;
    }
    // after loop: cf = head run length h
    metaS[tid] = (unsigned)cf | ((unsigned)firstLab << 6) | ((unsigned)lastLab << 7);
    __syncthreads();

    // ---- phase C: resolve trailing-run extension (expected 1 step) ----
    long long ext = 0;
    {
        int prevLast = lastLab;
        int t = tid + 1;
        bool open = true;
        while (t < BLOCK) {
            unsigned mb = metaS[t];
            if ((int)((mb >> 6) & 1) != prevLast) { open = false; break; }
            int hb = (int)(mb & 63);
            ext += hb;
            if (hb < K) { open = false; break; }    // run ends inside chunk t
            prevLast = (int)((mb >> 7) & 1);
            ++t;
        }
        if (open) {                                 // run reaches tile end (rare)
            long long g = (long long)(blockIdx.x + 1) * TILE;
            while (g < N_ELEM && labs[g] == prevLast) { ++ext; ++g; }
        }
    }
    double accd = (double)acc + (double)tce * (double)ext;

    // ---- phase D: block reduce, one float atomic per block ----
    for (int o = 32; o; o >>= 1) accd += __shfl_down(accd, o);
    int wid = tid >> 6, lane = tid & 63;
    if (lane == 0) wsum[wid] = accd;
    __syncthreads();
    if (tid == 0) {
        double s = 0.0;
        for (int w = 0; w < BLOCK / 64; ++w) s += wsum[w];
        atomicAdd(out, (float)(s * INV_N));
    }
}

extern "C" void kernel_launch(void* const* d_in, const int* in_sizes, int n_in,
                              void* d_out, int out_size, void* d_ws, size_t ws_size,
                              hipStream_t stream) {
    const float* inputs = (const float*)d_in[0];
    const int* labels = (const int*)d_in[1];
    float* out = (float*)d_out;

    hipMemsetAsync(out, 0, sizeof(float), stream);   // 0x0 == 0.0f
    k1_all<<<NBLK, BLOCK, 0, stream>>>(
        (const float4*)inputs, (const int4*)labels, labels, out);
}